// Round 16
// baseline (366.879 us; speedup 1.0000x reference)
//
#include <hip/hip_runtime.h>
#include <hip/hip_bf16.h>
#include <stdint.h>

// Problem: B=32, C=1024, H=W=32, S=1024, nh=1, hd=1024.
// out[b,o,s] = vsum[b,s] * sum_t Wp[o,t]*attn[b,t,s] + b_proj[o] + x[b,o,s]
// attn[t,s]  = E[t,s]/Z[t],  E[t,s]=exp(x_t^T M x_s / 32),  M = Wq^T Wk
// vsum[b,s]  = sum_c (sum_o Wv[o,c]) x[b,c,s]
// QK-path: logits = X^T M X with MT[c'][c]=sum_o Wq[o,c]Wk[o,c'].
// 1/Z[t] folded into Wp: wp_s[b][o][t] = Wp[o,t]/Z[b][t] (exact).
// GEMM: round-8/12 best-measured schedule. 256x256 tile, 8 waves, BK=64,
// 1 block/CU. Per K-tile 4 phases {reads + stage -> BAR -> lgkm0 ->
// 16 MFMA -> BAR}; stages A(t+1)@P1/P2, B(t+2)@P3/P4; vmcnt(4)@P4.
// Plateau model: per round = reads/2.3TB/s + ~22us compute, serialized;
// 8 structural variants failed to overlap (ledger r5/6/9/10/11/13/14).
// Round-16: vectorized k_xpose (float4 loads, short4 stores) — last
// dispatch with scalar-bf16 traffic (G13).

typedef __attribute__((ext_vector_type(8))) short short8;
typedef __attribute__((ext_vector_type(4))) short short4_t;
typedef __attribute__((ext_vector_type(4))) float f32x4;

__device__ __forceinline__ short f2b(float f) {
    __hip_bfloat16 h = __float2bfloat16(f);
    return *reinterpret_cast<short*>(&h);
}
__device__ __forceinline__ float b2f(short s) {
    __hip_bfloat16 h;
    *reinterpret_cast<short*>(&h) = s;
    return __bfloat162float(h);
}

#define GLOAD16(gp, lp) __builtin_amdgcn_global_load_lds(                      \
    (const __attribute__((address_space(1))) unsigned int*)(gp),               \
    (__attribute__((address_space(3))) unsigned int*)(lp), 16, 0, 0)

#define WAITV4 asm volatile("s_waitcnt vmcnt(4)" ::: "memory")
#define WAITV0 asm volatile("s_waitcnt vmcnt(0)" ::: "memory")
#define WAITL0 asm volatile("s_waitcnt lgkmcnt(0)" ::: "memory")
#define BAR()  { asm volatile("" ::: "memory"); __builtin_amdgcn_s_barrier(); \
                 asm volatile("" ::: "memory"); }

// ---- wvsum[c] += sum over 32-row chunk of w_qkv[2048+o][c]
__global__ void k_wvsum(const float* __restrict__ wqkv, float* __restrict__ wvsum) {
    int c = blockIdx.x * 256 + threadIdx.x;
    int o0 = blockIdx.y * 32;
    float s = 0.f;
    const float* p = wqkv + (size_t)(2048 + o0) * 1024 + c;
    #pragma unroll 8
    for (int o = 0; o < 32; ++o) s += p[(size_t)o * 1024];
    atomicAdd(&wvsum[c], s);
}

// ---- f32 -> bf16 convert (n multiple of 1024)
__global__ void k_cvt(const float* __restrict__ in, short* __restrict__ out) {
    int i = (blockIdx.x * 256 + threadIdx.x) * 4;
    #pragma unroll
    for (int j = 0; j < 4; ++j) out[i + j] = f2b(in[i + j]);
}

// ---- xT[b][s][c] = bf16(x[b][c][s]); vsum[b][s] += sum_c wvsum[c]*x[b][c][s]
// Vectorized: 128s x 32c tile per block; float4 loads, short4 stores.
// grid (8, 32, 32), 256 threads.
__global__ void k_xpose(const float* __restrict__ x, const float* __restrict__ wvsum,
                        short* __restrict__ xT, float* __restrict__ vsum) {
    __shared__ float tile[32][129];            // [c][s], pad 1 -> column reads clean
    __shared__ f32x4 ps[8][32];                // [ty][tx] partial vsum (4 s each)
    int b = blockIdx.z;
    int s0 = blockIdx.x * 128, c0 = blockIdx.y * 32;
    int t = threadIdx.x;
    const float* xb = x + ((size_t)b << 20);

    // load phase: tx = s-quad (0..31), ty = c-row base (0..7), 4 passes
    int tx = t & 31, ty = t >> 5;
    f32x4 acc = {0.f, 0.f, 0.f, 0.f};
    #pragma unroll
    for (int pass = 0; pass < 4; ++pass) {
        int cl = ty + pass * 8;
        f32x4 v = *(const f32x4*)&xb[(size_t)(c0 + cl) * 1024 + s0 + tx * 4];
        float w = wvsum[c0 + cl];
        #pragma unroll
        for (int j = 0; j < 4; ++j) tile[cl][tx * 4 + j] = v[j];
        acc += v * w;
    }
    ps[ty][tx] = acc;
    __syncthreads();

    if (ty == 0) {
        f32x4 s = ps[0][tx];
        #pragma unroll
        for (int i = 1; i < 8; ++i) s += ps[i][tx];
        #pragma unroll
        for (int j = 0; j < 4; ++j)
            atomicAdd(&vsum[b * 1024 + s0 + tx * 4 + j], s[j]);
    }

    // store phase: tcx = c-quad (0..7), tsy = s-row base (0..31), 4 passes
    int tcx = t & 7, tsy = t >> 3;
    short* xTb = xT + ((size_t)b << 20);
    #pragma unroll
    for (int pass = 0; pass < 4; ++pass) {
        int sl = tsy + pass * 32;
        short4_t r;
        #pragma unroll
        for (int j = 0; j < 4; ++j) r[j] = f2b(tile[tcx * 4 + j][sl]);
        *(short4_t*)&xTb[(size_t)(s0 + sl) * 1024 + c0 + tcx * 4] = r;
    }
}

// ---- WT[w][c][o] = bf16(wqkv[w*1024 + o][c]),  w=0:Wq  w=1:Wk
__global__ void k_xposew(const float* __restrict__ wqkv, short* __restrict__ WT) {
    __shared__ float tile[32][33];
    int w = blockIdx.z;
    int o0 = blockIdx.x * 32, c0 = blockIdx.y * 32;
    int tx = threadIdx.x, ty = threadIdx.y;
    const float* src = wqkv + (size_t)w * 1048576;
    #pragma unroll
    for (int i = 0; i < 4; ++i)
        tile[ty + i * 8][tx] = src[(size_t)(o0 + ty + i * 8) * 1024 + c0 + tx];
    __syncthreads();
    short* dst = WT + (size_t)w * 1048576;
    #pragma unroll
    for (int i = 0; i < 4; ++i) {
        int cl = ty + i * 8;
        dst[(size_t)(c0 + cl) * 1024 + o0 + tx] = f2b(tile[tx][cl]);
    }
}

// ---- MT[i] = bf16( sum_z partial[z][i] ),  8 partials of 1M f32
__global__ void k_red8(const float* __restrict__ part, short* __restrict__ MT) {
    int i4 = (blockIdx.x * 256 + threadIdx.x) * 4;
    f32x4 s = *(const f32x4*)&part[i4];
    #pragma unroll
    for (int z = 1; z < 8; ++z) s += *(const f32x4*)&part[(size_t)z * 1048576 + i4];
    short4_t r;
    #pragma unroll
    for (int j = 0; j < 4; ++j) r[j] = f2b(s[j]);
    *(short4_t*)&MT[i4] = r;
}

// ---- 256x256-tile bf16 GEMM, K = NT*64. D[i,j]=sum_k A[i,k]*Bt[j,k]
// MODE 0: store bf16 D           MODE 1: E=exp(D/32), Z[col]+=sums
// MODE 2: out=D*scale[col]+bias[row]+xres (f32)   MODE 3: store f32 D
template <int MODE, int TM, int TN, int NT>
__global__ __launch_bounds__(512, 2)
void k_gemm(const short* __restrict__ A0, size_t strideA, int lda,
            const short* __restrict__ B0, size_t strideB, int ldb,
            void* __restrict__ O0, size_t strideO, int ldo,
            float* __restrict__ Z,
            const float* __restrict__ scale,
            const float* __restrict__ bias,
            const float* __restrict__ xres) {
    __shared__ __align__(16) short As[2 * 256 * 64];
    __shared__ __align__(16) short Bs[2 * 256 * 64];

    constexpr int TPB = TM * TN;
    int wg = blockIdx.x;
    int cpx = gridDim.x >> 3;                  // bijective: nwg % 8 == 0
    int swz = (wg & 7) * cpx + (wg >> 3);
    int z = swz / TPB;
    int rz = swz - z * TPB;
    int m0 = (rz / TN) * 256, n0 = (rz % TN) * 256;

    int tid = threadIdx.x;
    int wid = tid >> 6, l = tid & 63;
    int wm = wid >> 2, wn = wid & 3;
    int lr = l & 15, lg = l >> 4;

    const short* A = A0 + (size_t)z * strideA;
    const short* Bt = B0 + (size_t)z * strideB;

    // staging: linear gload_lds dest + inverse-swizzled source + swizzled read
    int srow = wid * 16 + (l >> 3);
    int scol = ((l & 7) ^ (l >> 3)) * 8;
    const short* gA = A + (size_t)(m0 + srow) * lda + scol;
    const short* gB = Bt + (size_t)(n0 + srow) * ldb + scol;
    char* const ldsA = (char*)As;
    char* const ldsB = (char*)Bs;
    int sdst = wid * 2048;

    auto SA = [&](int buf, int h, int t) __attribute__((always_inline)) {
        const short* g = gA + (size_t)(h * 128) * lda + t * 64;
        char* d = ldsA + buf * 32768 + h * 16384 + sdst;
        GLOAD16(g, d);
        GLOAD16(g + (size_t)8 * lda, d + 1024);
    };
    auto SB = [&](int buf, int h, int t) __attribute__((always_inline)) {
        const short* g = gB + (size_t)(h * 128) * ldb + t * 64;
        char* d = ldsB + buf * 32768 + h * 16384 + sdst;
        GLOAD16(g, d);
        GLOAD16(g + (size_t)8 * ldb, d + 1024);
    };

    int cs0 = ((lg) ^ (lr & 7)) * 16;
    int cs1 = ((4 + lg) ^ (lr & 7)) * 16;
    int arow = (wm * 128 + lr) * 128;
    int brow = (wn * 64 + lr) * 128;

    short8 af[8], bf0[4], bf1[4];
    f32x4 acc[8][4] = {};

    auto RDA = [&](int buf, int mh) __attribute__((always_inline)) {
        const char* p = ldsA + buf * 32768 + arow + mh * 8192;
        #pragma unroll
        for (int mi = 0; mi < 4; ++mi) {
            af[mi * 2]     = *(const short8*)(p + mi * 2048 + cs0);
            af[mi * 2 + 1] = *(const short8*)(p + mi * 2048 + cs1);
        }
    };
    auto RDB = [&](short8* dst, int buf, int nh) __attribute__((always_inline)) {
        const char* p = ldsB + buf * 32768 + brow + nh * 4096;
        #pragma unroll
        for (int ni = 0; ni < 2; ++ni) {
            dst[ni * 2]     = *(const short8*)(p + ni * 2048 + cs0);
            dst[ni * 2 + 1] = *(const short8*)(p + ni * 2048 + cs1);
        }
    };
    auto MMA = [&](const short8* bfp, int mh, int nh) __attribute__((always_inline)) {
        __builtin_amdgcn_s_setprio(1);
        #pragma unroll
        for (int ks = 0; ks < 2; ++ks)
            #pragma unroll
            for (int mi = 0; mi < 4; ++mi)
                #pragma unroll
                for (int ni = 0; ni < 2; ++ni)
                    acc[mh * 4 + mi][nh * 2 + ni] =
                        __builtin_amdgcn_mfma_f32_16x16x32_bf16(
                            af[mi * 2 + ks], bfp[ni * 2 + ks],
                            acc[mh * 4 + mi][nh * 2 + ni], 0, 0, 0);
        __builtin_amdgcn_s_setprio(0);
    };

    // prologue: tile0 full (+ tile1 B halves when NT>1)
    SB(0, 0, 0); SB(0, 1, 0); SA(0, 0, 0); SA(0, 1, 0);
    if constexpr (NT > 1) {
        SB(1, 0, 1); SB(1, 1, 1);
        WAITV4;
    } else {
        WAITV0;
    }
    BAR();

    #pragma unroll 2
    for (int t = 0; t < NT - 2; ++t) {
        int b = t & 1;
        RDA(b, 0); RDB(bf0, b, 0); SA(b ^ 1, 0, t + 1);
        BAR(); WAITL0; MMA(bf0, 0, 0); BAR();
        RDB(bf1, b, 1); SA(b ^ 1, 1, t + 1);
        BAR(); WAITL0; MMA(bf1, 0, 1); BAR();
        RDA(b, 1); SB(b, 0, t + 2);
        BAR(); WAITL0; MMA(bf0, 1, 0); BAR();
        SB(b, 1, t + 2); WAITV4;
        BAR(); MMA(bf1, 1, 1); BAR();
    }
    if constexpr (NT > 1) {
        constexpr int b = (NT - 2) & 1;
        RDA(b, 0); RDB(bf0, b, 0); SA(b ^ 1, 0, NT - 1);
        BAR(); WAITL0; MMA(bf0, 0, 0); BAR();
        RDB(bf1, b, 1); SA(b ^ 1, 1, NT - 1);
        BAR(); WAITL0; MMA(bf1, 0, 1); BAR();
        RDA(b, 1);
        BAR(); WAITL0; MMA(bf0, 1, 0); BAR();
        WAITV0;
        BAR(); MMA(bf1, 1, 1); BAR();
    }
    {
        constexpr int b = (NT - 1) & 1;
        RDA(b, 0); RDB(bf0, b, 0);
        BAR(); WAITL0; MMA(bf0, 0, 0); BAR();
        RDB(bf1, b, 1);
        BAR(); WAITL0; MMA(bf1, 0, 1); BAR();
        RDA(b, 1);
        BAR(); WAITL0; MMA(bf0, 1, 0); BAR();
        MMA(bf1, 1, 1);
    }

    int rb = m0 + wm * 128, cb = n0 + wn * 64;
    if (MODE == 0) {
        short* O = (short*)O0 + (size_t)z * strideO;
        #pragma unroll
        for (int mi = 0; mi < 8; ++mi)
            #pragma unroll
            for (int ni = 0; ni < 4; ++ni)
                #pragma unroll
                for (int r = 0; r < 4; ++r)
                    O[(size_t)(rb + mi * 16 + lg * 4 + r) * ldo + cb + ni * 16 + lr] =
                        f2b(acc[mi][ni][r]);
    } else if (MODE == 1) {
        short* O = (short*)O0 + (size_t)z * strideO;
        float* Zb = Z + z * 1024;
        #pragma unroll
        for (int ni = 0; ni < 4; ++ni) {
            float zs = 0.f;
            #pragma unroll
            for (int mi = 0; mi < 8; ++mi)
                #pragma unroll
                for (int r = 0; r < 4; ++r) {
                    float ev = __expf(acc[mi][ni][r] * 0.03125f);
                    O[(size_t)(rb + mi * 16 + lg * 4 + r) * ldo + cb + ni * 16 + lr] = f2b(ev);
                    zs += ev;
                }
            zs += __shfl_xor(zs, 16);
            zs += __shfl_xor(zs, 32);
            if (l < 16) atomicAdd(&Zb[cb + ni * 16 + l], zs);
        }
    } else if (MODE == 2) {
        float* O = (float*)O0 + (size_t)z * strideO;
        const float* xr = xres + (size_t)z * strideO;
        #pragma unroll
        for (int mi = 0; mi < 8; ++mi)
            #pragma unroll
            for (int ni = 0; ni < 4; ++ni)
                #pragma unroll
                for (int r = 0; r < 4; ++r) {
                    int row = rb + mi * 16 + lg * 4 + r;
                    int col = cb + ni * 16 + lr;
                    O[(size_t)row * ldo + col] = acc[mi][ni][r] * scale[z * 1024 + col] +
                                                 bias[row] + xr[(size_t)row * ldo + col];
                }
    } else {
        float* O = (float*)O0 + (size_t)z * strideO;
        #pragma unroll
        for (int mi = 0; mi < 8; ++mi)
            #pragma unroll
            for (int ni = 0; ni < 4; ++ni)
                #pragma unroll
                for (int r = 0; r < 4; ++r)
                    O[(size_t)(rb + mi * 16 + lg * 4 + r) * ldo + cb + ni * 16 + lr] =
                        acc[mi][ni][r];
    }
}

// ---- wp_s[b][o][t] = wp_b[o][t] / Z[b][t]   (softmax 1/Z folded into Wp)
__global__ void k_wpscale(const short* __restrict__ wp_b, const float* __restrict__ Zr,
                          short* __restrict__ wp_s) {
    size_t i8 = ((size_t)blockIdx.x * 256 + threadIdx.x) * 8;  // flat [b][o][t]
    int b = (int)(i8 >> 20);
    int t0 = (int)(i8 & 1023);
    short8 w = *(const short8*)&wp_b[i8 & 1048575];
    const float* zp = Zr + b * 1024 + t0;
    short8 r;
    #pragma unroll
    for (int j = 0; j < 8; ++j) r[j] = f2b(b2f(w[j]) / zp[j]);
    *(short8*)&wp_s[i8] = r;
}

extern "C" void kernel_launch(void* const* d_in, const int* in_sizes, int n_in,
                              void* d_out, int out_size, void* d_ws, size_t ws_size,
                              hipStream_t stream) {
    const float* x     = (const float*)d_in[0];
    const float* wqkv  = (const float*)d_in[1];
    const float* wproj = (const float*)d_in[2];
    const float* bproj = (const float*)d_in[3];
    float* out = (float*)d_out;

    char* ws = (char*)d_ws;
    size_t off = 0;
    auto alloc = [&](size_t bytes) {
        void* p = ws + off;
        off += (bytes + 255) & ~(size_t)255;
        return p;
    };
    float* wvsum = (float*)alloc(1024 * 4);
    short* wp_b  = (short*)alloc((size_t)1024 * 1024 * 2);
    short* xT    = (short*)alloc((size_t)32 * 1024 * 1024 * 2);  // reused as wp_s later
    short* WT    = (short*)alloc((size_t)2 * 1024 * 1024 * 2);   // [WqT | WkT]
    float* MTp   = (float*)alloc((size_t)8 * 1024 * 1024 * 4);   // K-split partials
    short* MT    = (short*)alloc((size_t)1024 * 1024 * 2);       // MT[c'][c]
    short* YT    = (short*)alloc((size_t)32 * 1024 * 1024 * 2);
    short* attnT = (short*)alloc((size_t)32 * 1024 * 1024 * 2);
    float* vsum  = (float*)alloc(32 * 1024 * 4);
    float* Zbuf  = (float*)alloc(32 * 1024 * 4);

    hipMemsetAsync(wvsum, 0, 1024 * 4, stream);
    hipMemsetAsync(vsum, 0, 32 * 1024 * 4, stream);
    hipMemsetAsync(Zbuf, 0, 32 * 1024 * 4, stream);

    k_wvsum<<<dim3(4, 32), 256, 0, stream>>>(wqkv, wvsum);
    k_cvt<<<1024, 256, 0, stream>>>(wproj, wp_b);
    k_xposew<<<dim3(32, 32, 2), dim3(32, 8), 0, stream>>>(wqkv, WT);
    k_xpose<<<dim3(8, 32, 32), 256, 0, stream>>>(x, wvsum, xT, vsum);

    // MT partials: D[c'][c] = sum_{o in z-chunk} WkT[c',o]*WqT[c,o]  (K=128, z=8)
    k_gemm<3, 4, 4, 2><<<128, 512, 0, stream>>>(
        WT + 1048576, (size_t)128, 1024, WT, (size_t)128, 1024,
        MTp, (size_t)1048576, 1024, nullptr, nullptr, nullptr, nullptr);
    k_red8<<<1024, 256, 0, stream>>>(MTp, MT);

    // YT[b][t][c'] = sum_c xT[t,c]*MT[c',c]
    k_gemm<0, 4, 4, 16><<<512, 512, 0, stream>>>(
        xT, (size_t)1048576, 1024, MT, 0, 1024,
        YT, (size_t)1048576, 1024, nullptr, nullptr, nullptr, nullptr);

    // E[b][s][t] = exp(sum_c' xT[s,c']*YT[t,c'] / 32); Z[b][t] += col sums
    k_gemm<1, 4, 4, 16><<<512, 512, 0, stream>>>(
        xT, (size_t)1048576, 1024, YT, (size_t)1048576, 1024,
        attnT, (size_t)1048576, 1024, Zbuf, nullptr, nullptr, nullptr);

    // wp_s aliases xT (dead after the logits GEMM); 1/Z folded inline
    short* wp_s = xT;
    k_wpscale<<<16384, 256, 0, stream>>>(wp_b, Zbuf, wp_s);

    // out[b][o][s] = (sum_t wp_s[b][o,t]*E[t,s]) * vsum[s] + bias[o] + x[b][o][s]
    k_gemm<2, 4, 4, 16><<<512, 512, 0, stream>>>(
        wp_s, (size_t)1048576, 1024, attnT, (size_t)1048576, 1024,
        out, (size_t)1048576, 1024, nullptr, vsum, bproj, x);
}

// Round 17
// 359.938 us; speedup vs baseline: 1.0193x; 1.0193x over previous
//
#include <hip/hip_runtime.h>
#include <hip/hip_bf16.h>
#include <stdint.h>

// Problem: B=32, C=1024, H=W=32, S=1024, nh=1, hd=1024.
// out[b,o,s] = vsum[b,s] * sum_t Wp[o,t]*attn[b,t,s] + b_proj[o] + x[b,o,s]
// attn[t,s]  = E[t,s]/Z[t],  E[t,s]=exp(x_t^T M x_s / 32),  M = Wq^T Wk
// vsum[b,s]  = sum_c (sum_o Wv[o,c]) x[b,c,s]
// QK-path: logits = X^T M X with MT[c'][c]=sum_o Wq[o,c]Wk[o,c'].
// 1/Z[t] folded into Wp: wp_s[b][o][t] = Wp[o,t]/Z[b][t] (exact).
// GEMM: round-8/12 best-measured schedule. 256x256 tile, 8 waves, BK=64,
// 1 block/CU. Per K-tile 4 phases {reads + stage -> BAR -> lgkm0 ->
// 16 MFMA -> BAR}; stages A(t+1)@P1/P2, B(t+2)@P3/P4; vmcnt(4)@P4.
// Plateau: 9 structural variants (r5/6/9/10/11/13/14/16 + r3) all lost to
// this config; S x S GEMMs sit at ~118us (MfmaUtil 23%, FETCH=unique bytes).
// Round-17: revert k_xpose to r15 scalar (r16 vectorization regressed -6us);
// MT k-split 8->4 (halves MTp/red8 traffic).

typedef __attribute__((ext_vector_type(8))) short short8;
typedef __attribute__((ext_vector_type(4))) short short4_t;
typedef __attribute__((ext_vector_type(4))) float f32x4;

__device__ __forceinline__ short f2b(float f) {
    __hip_bfloat16 h = __float2bfloat16(f);
    return *reinterpret_cast<short*>(&h);
}
__device__ __forceinline__ float b2f(short s) {
    __hip_bfloat16 h;
    *reinterpret_cast<short*>(&h) = s;
    return __bfloat162float(h);
}

#define GLOAD16(gp, lp) __builtin_amdgcn_global_load_lds(                      \
    (const __attribute__((address_space(1))) unsigned int*)(gp),               \
    (__attribute__((address_space(3))) unsigned int*)(lp), 16, 0, 0)

#define WAITV4 asm volatile("s_waitcnt vmcnt(4)" ::: "memory")
#define WAITV0 asm volatile("s_waitcnt vmcnt(0)" ::: "memory")
#define WAITL0 asm volatile("s_waitcnt lgkmcnt(0)" ::: "memory")
#define BAR()  { asm volatile("" ::: "memory"); __builtin_amdgcn_s_barrier(); \
                 asm volatile("" ::: "memory"); }

// ---- wvsum[c] += sum over 32-row chunk of w_qkv[2048+o][c]
__global__ void k_wvsum(const float* __restrict__ wqkv, float* __restrict__ wvsum) {
    int c = blockIdx.x * 256 + threadIdx.x;
    int o0 = blockIdx.y * 32;
    float s = 0.f;
    const float* p = wqkv + (size_t)(2048 + o0) * 1024 + c;
    #pragma unroll 8
    for (int o = 0; o < 32; ++o) s += p[(size_t)o * 1024];
    atomicAdd(&wvsum[c], s);
}

// ---- f32 -> bf16 convert (n multiple of 1024)
__global__ void k_cvt(const float* __restrict__ in, short* __restrict__ out) {
    int i = (blockIdx.x * 256 + threadIdx.x) * 4;
    #pragma unroll
    for (int j = 0; j < 4; ++j) out[i + j] = f2b(in[i + j]);
}

// ---- xT[b][s][c] = bf16(x[b][c][s]); vsum[b][s] += sum_c wvsum[c]*x[b][c][s]
// (round-15 proven version; r16 vectorized variant regressed)
__global__ void k_xpose(const float* __restrict__ x, const float* __restrict__ wvsum,
                        short* __restrict__ xT, float* __restrict__ vsum) {
    __shared__ float tile[32][33];
    __shared__ float ps[8][32];
    int b = blockIdx.z;
    int s0 = blockIdx.x * 32, c0 = blockIdx.y * 32;
    int tx = threadIdx.x, ty = threadIdx.y;
    const float* xb = x + ((size_t)b << 20);
    float p = 0.f;
    #pragma unroll
    for (int i = 0; i < 4; ++i) {
        int cl = ty + i * 8;
        float v = xb[(size_t)(c0 + cl) * 1024 + s0 + tx];
        tile[cl][tx] = v;
        p += v * wvsum[c0 + cl];
    }
    ps[ty][tx] = p;
    __syncthreads();
    short* xTb = xT + ((size_t)b << 20);
    #pragma unroll
    for (int i = 0; i < 4; ++i) {
        int sl = ty + i * 8;
        xTb[(size_t)(s0 + sl) * 1024 + c0 + tx] = f2b(tile[tx][sl]);
    }
    if (ty == 0) {
        float s = 0.f;
        #pragma unroll
        for (int i = 0; i < 8; ++i) s += ps[i][tx];
        atomicAdd(&vsum[b * 1024 + s0 + tx], s);
    }
}

// ---- WT[w][c][o] = bf16(wqkv[w*1024 + o][c]),  w=0:Wq  w=1:Wk
__global__ void k_xposew(const float* __restrict__ wqkv, short* __restrict__ WT) {
    __shared__ float tile[32][33];
    int w = blockIdx.z;
    int o0 = blockIdx.x * 32, c0 = blockIdx.y * 32;
    int tx = threadIdx.x, ty = threadIdx.y;
    const float* src = wqkv + (size_t)w * 1048576;
    #pragma unroll
    for (int i = 0; i < 4; ++i)
        tile[ty + i * 8][tx] = src[(size_t)(o0 + ty + i * 8) * 1024 + c0 + tx];
    __syncthreads();
    short* dst = WT + (size_t)w * 1048576;
    #pragma unroll
    for (int i = 0; i < 4; ++i) {
        int cl = ty + i * 8;
        dst[(size_t)(c0 + cl) * 1024 + o0 + tx] = f2b(tile[tx][cl]);
    }
}

// ---- MT[i] = bf16( sum_z partial[z][i] ),  4 partials of 1M f32
__global__ void k_red4(const float* __restrict__ part, short* __restrict__ MT) {
    int i4 = (blockIdx.x * 256 + threadIdx.x) * 4;
    f32x4 s = *(const f32x4*)&part[i4];
    #pragma unroll
    for (int z = 1; z < 4; ++z) s += *(const f32x4*)&part[(size_t)z * 1048576 + i4];
    short4_t r;
    #pragma unroll
    for (int j = 0; j < 4; ++j) r[j] = f2b(s[j]);
    *(short4_t*)&MT[i4] = r;
}

// ---- 256x256-tile bf16 GEMM, K = NT*64. D[i,j]=sum_k A[i,k]*Bt[j,k]
// MODE 0: store bf16 D           MODE 1: E=exp(D/32), Z[col]+=sums
// MODE 2: out=D*scale[col]+bias[row]+xres (f32)   MODE 3: store f32 D
template <int MODE, int TM, int TN, int NT>
__global__ __launch_bounds__(512, 2)
void k_gemm(const short* __restrict__ A0, size_t strideA, int lda,
            const short* __restrict__ B0, size_t strideB, int ldb,
            void* __restrict__ O0, size_t strideO, int ldo,
            float* __restrict__ Z,
            const float* __restrict__ scale,
            const float* __restrict__ bias,
            const float* __restrict__ xres) {
    __shared__ __align__(16) short As[2 * 256 * 64];
    __shared__ __align__(16) short Bs[2 * 256 * 64];

    constexpr int TPB = TM * TN;
    int wg = blockIdx.x;
    int cpx = gridDim.x >> 3;                  // bijective: nwg % 8 == 0
    int swz = (wg & 7) * cpx + (wg >> 3);
    int z = swz / TPB;
    int rz = swz - z * TPB;
    int m0 = (rz / TN) * 256, n0 = (rz % TN) * 256;

    int tid = threadIdx.x;
    int wid = tid >> 6, l = tid & 63;
    int wm = wid >> 2, wn = wid & 3;
    int lr = l & 15, lg = l >> 4;

    const short* A = A0 + (size_t)z * strideA;
    const short* Bt = B0 + (size_t)z * strideB;

    // staging: linear gload_lds dest + inverse-swizzled source + swizzled read
    int srow = wid * 16 + (l >> 3);
    int scol = ((l & 7) ^ (l >> 3)) * 8;
    const short* gA = A + (size_t)(m0 + srow) * lda + scol;
    const short* gB = Bt + (size_t)(n0 + srow) * ldb + scol;
    char* const ldsA = (char*)As;
    char* const ldsB = (char*)Bs;
    int sdst = wid * 2048;

    auto SA = [&](int buf, int h, int t) __attribute__((always_inline)) {
        const short* g = gA + (size_t)(h * 128) * lda + t * 64;
        char* d = ldsA + buf * 32768 + h * 16384 + sdst;
        GLOAD16(g, d);
        GLOAD16(g + (size_t)8 * lda, d + 1024);
    };
    auto SB = [&](int buf, int h, int t) __attribute__((always_inline)) {
        const short* g = gB + (size_t)(h * 128) * ldb + t * 64;
        char* d = ldsB + buf * 32768 + h * 16384 + sdst;
        GLOAD16(g, d);
        GLOAD16(g + (size_t)8 * ldb, d + 1024);
    };

    int cs0 = ((lg) ^ (lr & 7)) * 16;
    int cs1 = ((4 + lg) ^ (lr & 7)) * 16;
    int arow = (wm * 128 + lr) * 128;
    int brow = (wn * 64 + lr) * 128;

    short8 af[8], bf0[4], bf1[4];
    f32x4 acc[8][4] = {};

    auto RDA = [&](int buf, int mh) __attribute__((always_inline)) {
        const char* p = ldsA + buf * 32768 + arow + mh * 8192;
        #pragma unroll
        for (int mi = 0; mi < 4; ++mi) {
            af[mi * 2]     = *(const short8*)(p + mi * 2048 + cs0);
            af[mi * 2 + 1] = *(const short8*)(p + mi * 2048 + cs1);
        }
    };
    auto RDB = [&](short8* dst, int buf, int nh) __attribute__((always_inline)) {
        const char* p = ldsB + buf * 32768 + brow + nh * 4096;
        #pragma unroll
        for (int ni = 0; ni < 2; ++ni) {
            dst[ni * 2]     = *(const short8*)(p + ni * 2048 + cs0);
            dst[ni * 2 + 1] = *(const short8*)(p + ni * 2048 + cs1);
        }
    };
    auto MMA = [&](const short8* bfp, int mh, int nh) __attribute__((always_inline)) {
        __builtin_amdgcn_s_setprio(1);
        #pragma unroll
        for (int ks = 0; ks < 2; ++ks)
            #pragma unroll
            for (int mi = 0; mi < 4; ++mi)
                #pragma unroll
                for (int ni = 0; ni < 2; ++ni)
                    acc[mh * 4 + mi][nh * 2 + ni] =
                        __builtin_amdgcn_mfma_f32_16x16x32_bf16(
                            af[mi * 2 + ks], bfp[ni * 2 + ks],
                            acc[mh * 4 + mi][nh * 2 + ni], 0, 0, 0);
        __builtin_amdgcn_s_setprio(0);
    };

    // prologue: tile0 full (+ tile1 B halves when NT>1)
    SB(0, 0, 0); SB(0, 1, 0); SA(0, 0, 0); SA(0, 1, 0);
    if constexpr (NT > 1) {
        SB(1, 0, 1); SB(1, 1, 1);
        WAITV4;
    } else {
        WAITV0;
    }
    BAR();

    #pragma unroll 2
    for (int t = 0; t < NT - 2; ++t) {
        int b = t & 1;
        RDA(b, 0); RDB(bf0, b, 0); SA(b ^ 1, 0, t + 1);
        BAR(); WAITL0; MMA(bf0, 0, 0); BAR();
        RDB(bf1, b, 1); SA(b ^ 1, 1, t + 1);
        BAR(); WAITL0; MMA(bf1, 0, 1); BAR();
        RDA(b, 1); SB(b, 0, t + 2);
        BAR(); WAITL0; MMA(bf0, 1, 0); BAR();
        SB(b, 1, t + 2); WAITV4;
        BAR(); MMA(bf1, 1, 1); BAR();
    }
    if constexpr (NT > 1) {
        constexpr int b = (NT - 2) & 1;
        RDA(b, 0); RDB(bf0, b, 0); SA(b ^ 1, 0, NT - 1);
        BAR(); WAITL0; MMA(bf0, 0, 0); BAR();
        RDB(bf1, b, 1); SA(b ^ 1, 1, NT - 1);
        BAR(); WAITL0; MMA(bf1, 0, 1); BAR();
        RDA(b, 1);
        BAR(); WAITL0; MMA(bf0, 1, 0); BAR();
        WAITV0;
        BAR(); MMA(bf1, 1, 1); BAR();
    }
    {
        constexpr int b = (NT - 1) & 1;
        RDA(b, 0); RDB(bf0, b, 0);
        BAR(); WAITL0; MMA(bf0, 0, 0); BAR();
        RDB(bf1, b, 1);
        BAR(); WAITL0; MMA(bf1, 0, 1); BAR();
        RDA(b, 1);
        BAR(); WAITL0; MMA(bf0, 1, 0); BAR();
        MMA(bf1, 1, 1);
    }

    int rb = m0 + wm * 128, cb = n0 + wn * 64;
    if (MODE == 0) {
        short* O = (short*)O0 + (size_t)z * strideO;
        #pragma unroll
        for (int mi = 0; mi < 8; ++mi)
            #pragma unroll
            for (int ni = 0; ni < 4; ++ni)
                #pragma unroll
                for (int r = 0; r < 4; ++r)
                    O[(size_t)(rb + mi * 16 + lg * 4 + r) * ldo + cb + ni * 16 + lr] =
                        f2b(acc[mi][ni][r]);
    } else if (MODE == 1) {
        short* O = (short*)O0 + (size_t)z * strideO;
        float* Zb = Z + z * 1024;
        #pragma unroll
        for (int ni = 0; ni < 4; ++ni) {
            float zs = 0.f;
            #pragma unroll
            for (int mi = 0; mi < 8; ++mi)
                #pragma unroll
                for (int r = 0; r < 4; ++r) {
                    float ev = __expf(acc[mi][ni][r] * 0.03125f);
                    O[(size_t)(rb + mi * 16 + lg * 4 + r) * ldo + cb + ni * 16 + lr] = f2b(ev);
                    zs += ev;
                }
            zs += __shfl_xor(zs, 16);
            zs += __shfl_xor(zs, 32);
            if (l < 16) atomicAdd(&Zb[cb + ni * 16 + l], zs);
        }
    } else if (MODE == 2) {
        float* O = (float*)O0 + (size_t)z * strideO;
        const float* xr = xres + (size_t)z * strideO;
        #pragma unroll
        for (int mi = 0; mi < 8; ++mi)
            #pragma unroll
            for (int ni = 0; ni < 4; ++ni)
                #pragma unroll
                for (int r = 0; r < 4; ++r) {
                    int row = rb + mi * 16 + lg * 4 + r;
                    int col = cb + ni * 16 + lr;
                    O[(size_t)row * ldo + col] = acc[mi][ni][r] * scale[z * 1024 + col] +
                                                 bias[row] + xr[(size_t)row * ldo + col];
                }
    } else {
        float* O = (float*)O0 + (size_t)z * strideO;
        #pragma unroll
        for (int mi = 0; mi < 8; ++mi)
            #pragma unroll
            for (int ni = 0; ni < 4; ++ni)
                #pragma unroll
                for (int r = 0; r < 4; ++r)
                    O[(size_t)(rb + mi * 16 + lg * 4 + r) * ldo + cb + ni * 16 + lr] =
                        acc[mi][ni][r];
    }
}

// ---- wp_s[b][o][t] = wp_b[o][t] / Z[b][t]   (softmax 1/Z folded into Wp)
__global__ void k_wpscale(const short* __restrict__ wp_b, const float* __restrict__ Zr,
                          short* __restrict__ wp_s) {
    size_t i8 = ((size_t)blockIdx.x * 256 + threadIdx.x) * 8;  // flat [b][o][t]
    int b = (int)(i8 >> 20);
    int t0 = (int)(i8 & 1023);
    short8 w = *(const short8*)&wp_b[i8 & 1048575];
    const float* zp = Zr + b * 1024 + t0;
    short8 r;
    #pragma unroll
    for (int j = 0; j < 8; ++j) r[j] = f2b(b2f(w[j]) / zp[j]);
    *(short8*)&wp_s[i8] = r;
}

extern "C" void kernel_launch(void* const* d_in, const int* in_sizes, int n_in,
                              void* d_out, int out_size, void* d_ws, size_t ws_size,
                              hipStream_t stream) {
    const float* x     = (const float*)d_in[0];
    const float* wqkv  = (const float*)d_in[1];
    const float* wproj = (const float*)d_in[2];
    const float* bproj = (const float*)d_in[3];
    float* out = (float*)d_out;

    char* ws = (char*)d_ws;
    size_t off = 0;
    auto alloc = [&](size_t bytes) {
        void* p = ws + off;
        off += (bytes + 255) & ~(size_t)255;
        return p;
    };
    float* wvsum = (float*)alloc(1024 * 4);
    short* wp_b  = (short*)alloc((size_t)1024 * 1024 * 2);
    short* xT    = (short*)alloc((size_t)32 * 1024 * 1024 * 2);  // reused as wp_s later
    short* WT    = (short*)alloc((size_t)2 * 1024 * 1024 * 2);   // [WqT | WkT]
    float* MTp   = (float*)alloc((size_t)4 * 1024 * 1024 * 4);   // K-split partials (z=4)
    short* MT    = (short*)alloc((size_t)1024 * 1024 * 2);       // MT[c'][c]
    short* YT    = (short*)alloc((size_t)32 * 1024 * 1024 * 2);
    short* attnT = (short*)alloc((size_t)32 * 1024 * 1024 * 2);
    float* vsum  = (float*)alloc(32 * 1024 * 4);
    float* Zbuf  = (float*)alloc(32 * 1024 * 4);

    hipMemsetAsync(wvsum, 0, 1024 * 4, stream);
    hipMemsetAsync(vsum, 0, 32 * 1024 * 4, stream);
    hipMemsetAsync(Zbuf, 0, 32 * 1024 * 4, stream);

    k_wvsum<<<dim3(4, 32), 256, 0, stream>>>(wqkv, wvsum);
    k_cvt<<<1024, 256, 0, stream>>>(wproj, wp_b);
    k_xposew<<<dim3(32, 32, 2), dim3(32, 8), 0, stream>>>(wqkv, WT);
    k_xpose<<<dim3(32, 32, 32), dim3(32, 8), 0, stream>>>(x, wvsum, xT, vsum);

    // MT partials: D[c'][c] = sum_{o in z-chunk} WkT[c',o]*WqT[c,o]  (K=256, z=4)
    k_gemm<3, 4, 4, 4><<<64, 512, 0, stream>>>(
        WT + 1048576, (size_t)256, 1024, WT, (size_t)256, 1024,
        MTp, (size_t)1048576, 1024, nullptr, nullptr, nullptr, nullptr);
    k_red4<<<1024, 256, 0, stream>>>(MTp, MT);

    // YT[b][t][c'] = sum_c xT[t,c]*MT[c',c]
    k_gemm<0, 4, 4, 16><<<512, 512, 0, stream>>>(
        xT, (size_t)1048576, 1024, MT, 0, 1024,
        YT, (size_t)1048576, 1024, nullptr, nullptr, nullptr, nullptr);

    // E[b][s][t] = exp(sum_c' xT[s,c']*YT[t,c'] / 32); Z[b][t] += col sums
    k_gemm<1, 4, 4, 16><<<512, 512, 0, stream>>>(
        xT, (size_t)1048576, 1024, YT, (size_t)1048576, 1024,
        attnT, (size_t)1048576, 1024, Zbuf, nullptr, nullptr, nullptr);

    // wp_s aliases xT (dead after the logits GEMM); 1/Z folded inline
    short* wp_s = xT;
    k_wpscale<<<16384, 256, 0, stream>>>(wp_b, Zbuf, wp_s);

    // out[b][o][s] = (sum_t wp_s[b][o,t]*E[t,s]) * vsum[s] + bias[o] + x[b][o][s]
    k_gemm<2, 4, 4, 16><<<512, 512, 0, stream>>>(
        wp_s, (size_t)1048576, 1024, attnT, (size_t)1048576, 1024,
        out, (size_t)1048576, 1024, nullptr, vsum, bproj, x);
}